// Round 12
// baseline (236.371 us; speedup 1.0000x reference)
//
#include <hip/hip_runtime.h>
#include <math.h>

// Problem constants (B=2,H=12,Q=2048,K=2048,D=128,NPOS=512)
#define DD    128
#define NPOS  512
#define KK    2048
#define RPB   16        // rows per block in table/fused kernel (MFMA M)
#define BLK   1024
#define SRPB  8         // rows per block in stream kernel
#define SBLK  512

typedef __attribute__((ext_vector_type(8))) short short8_t;  // 8 bf16
typedef __attribute__((ext_vector_type(4))) float f32x4;

union BfPack {
    unsigned u[4];
    short8_t v;
};

__device__ __forceinline__ float sigmoidf_fast(float x) {
    return __builtin_amdgcn_rcpf(1.0f + __expf(-x));
}

__device__ __forceinline__ unsigned pack_bf16(float lo, float hi) {
    return (__float_as_uint(hi) & 0xffff0000u) | (__float_as_uint(lo) >> 16);
}

__device__ __forceinline__ unsigned short bf16_trunc(float x) {
    return (unsigned short)(__float_as_uint(x) >> 16);
}

__device__ __forceinline__ float bf16_to_f32(unsigned short u) {
    return __uint_as_float(((unsigned)u) << 16);
}

// ---------------------------------------------------------------------------
// Kernel A: logits_int table via bf16 MFMA -> d_ws as bf16 [R][NPOS]
// ---------------------------------------------------------------------------
__global__ __launch_bounds__(BLK, 8)
void cope_table(const float* __restrict__ query,
                const float* __restrict__ pos_emb,
                unsigned short* __restrict__ table)
{
    const int t    = threadIdx.x;
    const int wv   = t >> 6;
    const int lane = t & 63;

    const size_t row_base = (size_t)blockIdx.x * RPB;

    const int m  = lane & 15;
    const int g  = lane >> 4;
    const int n0 = wv * 32 + m;

    f32x4 acc0 = {0.f, 0.f, 0.f, 0.f};
    f32x4 acc1 = {0.f, 0.f, 0.f, 0.f};

    #pragma unroll
    for (int kk = 0; kk < 4; ++kk) {
        const int k0 = kk * 32 + g * 8;

        const float* qp = query + (row_base + m) * DD + k0;
        f32x4 a0 = *reinterpret_cast<const f32x4*>(qp);
        f32x4 a1 = *reinterpret_cast<const f32x4*>(qp + 4);
        BfPack af;
        af.u[0] = pack_bf16(a0.x, a0.y);
        af.u[1] = pack_bf16(a0.z, a0.w);
        af.u[2] = pack_bf16(a1.x, a1.y);
        af.u[3] = pack_bf16(a1.z, a1.w);

        const float* bp = pos_emb + (size_t)k0 * NPOS + n0;
        float b0[8], b1[8];
        #pragma unroll
        for (int j = 0; j < 8; ++j) {
            b0[j] = bp[(size_t)j * NPOS];
            b1[j] = bp[(size_t)j * NPOS + 16];
        }
        BfPack bf0, bf1;
        #pragma unroll
        for (int j = 0; j < 4; ++j) {
            bf0.u[j] = pack_bf16(b0[2 * j], b0[2 * j + 1]);
            bf1.u[j] = pack_bf16(b1[2 * j], b1[2 * j + 1]);
        }

        acc0 = __builtin_amdgcn_mfma_f32_16x16x32_bf16(af.v, bf0.v, acc0, 0, 0, 0);
        acc1 = __builtin_amdgcn_mfma_f32_16x16x32_bf16(af.v, bf1.v, acc1, 0, 0, 0);
    }

    #pragma unroll
    for (int r = 0; r < 4; ++r) {
        const size_t ro = (row_base + g * 4 + r) * (size_t)NPOS;
        table[ro + n0]      = bf16_trunc(acc0[r]);
        table[ro + n0 + 16] = bf16_trunc(acc1[r]);
    }
}

// ---------------------------------------------------------------------------
// Kernel B: barrier-free streamer. Each wave stages ITS OWN row's table into
// LDS (wave-private => no __syncthreads), then scan+gather+store (R8 phase 2).
// ---------------------------------------------------------------------------
__global__ __launch_bounds__(SBLK, 8)
void cope_stream(const unsigned short* __restrict__ table,
                 const float* __restrict__ attn,
                 const int*   __restrict__ npos_max_p,
                 float* __restrict__ out)
{
    const int t    = threadIdx.x;
    const int wv   = t >> 6;        // 0..7, one row per wave
    const int lane = t & 63;

    __shared__ float s_tab[SRPB][NPOS + 1];

    const size_t row  = (size_t)blockIdx.x * SRPB + wv;
    const float* arow = attn + row * (size_t)KK;
    float*       orow = out  + row * (size_t)KK;
    float*       tab  = s_tab[wv];

    // stage this wave's table row: 8 coalesced 128B loads, conflict-free LDS
    {
        const unsigned short* trow = table + row * (size_t)NPOS;
        #pragma unroll
        for (int j = 0; j < 8; ++j)
            tab[lane + j * 64] = bf16_to_f32(trow[lane + j * 64]);
        if (lane == 0) tab[NPOS] = 0.0f;   // sentinel
    }
    // no barrier: wave reads only what it wrote; compiler inserts lgkmcnt.

    const float clampv = (float)(*npos_max_p - 1);

    float suff[8][4];
    float lct[8];
    float incl[8];

    #pragma unroll
    for (int c = 0; c < 8; ++c) {
        f32x4 gv = *reinterpret_cast<const f32x4*>(arow + c * 256 + lane * 4);
        float s0 = sigmoidf_fast(gv.x);
        float s1 = sigmoidf_fast(gv.y);
        float s2 = sigmoidf_fast(gv.z);
        float s3 = sigmoidf_fast(gv.w);
        suff[c][3] = s3;
        suff[c][2] = s2 + suff[c][3];
        suff[c][1] = s1 + suff[c][2];
        suff[c][0] = s0 + suff[c][1];
        lct[c] = suff[c][0];

        float v = lct[c];
        #pragma unroll
        for (int off = 1; off < 64; off <<= 1) {
            float u = __shfl_down(v, off);
            if (lane + off < 64) v += u;
        }
        incl[c] = v;
    }

    float Tc[8];
    #pragma unroll
    for (int c = 0; c < 8; ++c) Tc[c] = __shfl(incl[c], 0);
    float offc[8];
    offc[7] = 0.0f;
    #pragma unroll
    for (int c = 6; c >= 0; --c) offc[c] = offc[c + 1] + Tc[c + 1];

    #pragma unroll
    for (int c = 0; c < 8; ++c) {
        float base = offc[c] + (incl[c] - lct[c]);
        f32x4 res;
        #pragma unroll
        for (int j = 0; j < 4; ++j) {
            float pos = fminf(suff[c][j] + base, clampv);
            int   ifl = (int)pos;
            float wgt = pos - (float)ifl;
            float lf  = tab[ifl];
            float lc  = tab[ifl + 1];
            res[j] = fmaf(wgt, lc - lf, lf);
        }
        __builtin_nontemporal_store(res,
            reinterpret_cast<f32x4*>(orow + c * 256 + lane * 4));
    }
}

// ---------------------------------------------------------------------------
// Fallback: R8 fused champion (used only if ws_size is too small)
// ---------------------------------------------------------------------------
__global__ __launch_bounds__(BLK, 8)
void cope_fused(const float* __restrict__ query,
                const float* __restrict__ attn,
                const float* __restrict__ pos_emb,
                const int*   __restrict__ npos_max_p,
                float* __restrict__ out)
{
    const int t    = threadIdx.x;
    const int wv   = t >> 6;
    const int lane = t & 63;

    __shared__ float s_tab[RPB][NPOS + 1];

    const size_t row_base = (size_t)blockIdx.x * RPB;

    {
        const int m  = lane & 15;
        const int g  = lane >> 4;
        const int n0 = wv * 32 + m;

        f32x4 acc0 = {0.f, 0.f, 0.f, 0.f};
        f32x4 acc1 = {0.f, 0.f, 0.f, 0.f};

        #pragma unroll
        for (int kk = 0; kk < 4; ++kk) {
            const int k0 = kk * 32 + g * 8;
            const float* qp = query + (row_base + m) * DD + k0;
            f32x4 a0 = *reinterpret_cast<const f32x4*>(qp);
            f32x4 a1 = *reinterpret_cast<const f32x4*>(qp + 4);
            BfPack af;
            af.u[0] = pack_bf16(a0.x, a0.y);
            af.u[1] = pack_bf16(a0.z, a0.w);
            af.u[2] = pack_bf16(a1.x, a1.y);
            af.u[3] = pack_bf16(a1.z, a1.w);

            const float* bp = pos_emb + (size_t)k0 * NPOS + n0;
            float b0[8], b1[8];
            #pragma unroll
            for (int j = 0; j < 8; ++j) {
                b0[j] = bp[(size_t)j * NPOS];
                b1[j] = bp[(size_t)j * NPOS + 16];
            }
            BfPack bf0, bf1;
            #pragma unroll
            for (int j = 0; j < 4; ++j) {
                bf0.u[j] = pack_bf16(b0[2 * j], b0[2 * j + 1]);
                bf1.u[j] = pack_bf16(b1[2 * j], b1[2 * j + 1]);
            }
            acc0 = __builtin_amdgcn_mfma_f32_16x16x32_bf16(af.v, bf0.v, acc0, 0, 0, 0);
            acc1 = __builtin_amdgcn_mfma_f32_16x16x32_bf16(af.v, bf1.v, acc1, 0, 0, 0);
        }

        #pragma unroll
        for (int r = 0; r < 4; ++r) {
            s_tab[g * 4 + r][n0]      = acc0[r];
            s_tab[g * 4 + r][n0 + 16] = acc1[r];
        }
        if (t < RPB) s_tab[t][NPOS] = 0.0f;
    }
    __syncthreads();

    const size_t row = row_base + wv;
    const float* arow = attn + row * (size_t)KK;
    float*       orow = out  + row * (size_t)KK;
    const float* tab  = s_tab[wv];

    const float clampv = (float)(*npos_max_p - 1);

    float suff[8][4];
    float lct[8];
    float incl[8];

    #pragma unroll
    for (int c = 0; c < 8; ++c) {
        f32x4 gv = *reinterpret_cast<const f32x4*>(arow + c * 256 + lane * 4);
        float s0 = sigmoidf_fast(gv.x);
        float s1 = sigmoidf_fast(gv.y);
        float s2 = sigmoidf_fast(gv.z);
        float s3 = sigmoidf_fast(gv.w);
        suff[c][3] = s3;
        suff[c][2] = s2 + suff[c][3];
        suff[c][1] = s1 + suff[c][2];
        suff[c][0] = s0 + suff[c][1];
        lct[c] = suff[c][0];

        float v = lct[c];
        #pragma unroll
        for (int off = 1; off < 64; off <<= 1) {
            float u = __shfl_down(v, off);
            if (lane + off < 64) v += u;
        }
        incl[c] = v;
    }

    float Tc[8];
    #pragma unroll
    for (int c = 0; c < 8; ++c) Tc[c] = __shfl(incl[c], 0);
    float offc[8];
    offc[7] = 0.0f;
    #pragma unroll
    for (int c = 6; c >= 0; --c) offc[c] = offc[c + 1] + Tc[c + 1];

    #pragma unroll
    for (int c = 0; c < 8; ++c) {
        float base = offc[c] + (incl[c] - lct[c]);
        f32x4 res;
        #pragma unroll
        for (int j = 0; j < 4; ++j) {
            float pos = fminf(suff[c][j] + base, clampv);
            int   ifl = (int)pos;
            float wgt = pos - (float)ifl;
            float lf  = tab[ifl];
            float lc  = tab[ifl + 1];
            res[j] = fmaf(wgt, lc - lf, lf);
        }
        __builtin_nontemporal_store(res, reinterpret_cast<f32x4*>(orow + c * 256 + lane * 4));
    }
}

extern "C" void kernel_launch(void* const* d_in, const int* in_sizes, int n_in,
                              void* d_out, int out_size, void* d_ws, size_t ws_size,
                              hipStream_t stream) {
    const float* query   = (const float*)d_in[0];
    const float* attn    = (const float*)d_in[1];
    const float* pos_emb = (const float*)d_in[2];
    const int*   nposp   = (const int*)d_in[3];
    float*       outp    = (float*)d_out;

    const int rows = in_sizes[1] / KK;   // B*H*Q = 49152
    const size_t table_bytes = (size_t)rows * NPOS * sizeof(unsigned short);

    if (ws_size >= table_bytes) {
        unsigned short* table = (unsigned short*)d_ws;
        cope_table<<<rows / RPB, BLK, 0, stream>>>(query, pos_emb, table);
        cope_stream<<<rows / SRPB, SBLK, 0, stream>>>(table, attn, nposp, outp);
    } else {
        cope_fused<<<rows / RPB, BLK, 0, stream>>>(query, attn, pos_emb, nposp, outp);
    }
}

// Round 13
// 191.203 us; speedup vs baseline: 1.2362x; 1.2362x over previous
//
#include <hip/hip_runtime.h>
#include <math.h>

// Problem constants (B=2,H=12,Q=2048,K=2048,D=128,NPOS=512)
#define DD    128
#define NPOS  512
#define KK    2048
#define RPB   16        // rows per block = MFMA M dimension
#define BLK   1024      // 16 waves: one wave per row in phase 2

typedef __attribute__((ext_vector_type(8))) short short8_t;  // 8 bf16
typedef __attribute__((ext_vector_type(4))) float f32x4;

union BfPack {
    unsigned u[4];
    short8_t v;
};

__device__ __forceinline__ float sigmoidf_fast(float x) {
    return __builtin_amdgcn_rcpf(1.0f + __expf(-x));
}

__device__ __forceinline__ unsigned pack_bf16(float lo, float hi) {
    return (__float_as_uint(hi) & 0xffff0000u) | (__float_as_uint(lo) >> 16);
}

// one DPP-add step: x += dpp_mov(x); old=0 & bound_ctrl=false -> identity 0
template <int CTRL, int ROW_MASK>
__device__ __forceinline__ float dpp_add(float x) {
    int t = __builtin_amdgcn_update_dpp(0, __float_as_int(x),
                                        CTRL, ROW_MASK, 0xf, false);
    return x + __int_as_float(t);
}

// wave64 inclusive PREFIX scan, pure VALU (verified correct in R11)
__device__ __forceinline__ float wave_prefix_incl(float x) {
    x = dpp_add<0x111, 0xf>(x);   // row_shr:1
    x = dpp_add<0x112, 0xf>(x);   // row_shr:2
    x = dpp_add<0x114, 0xf>(x);   // row_shr:4
    x = dpp_add<0x118, 0xf>(x);   // row_shr:8
    x = dpp_add<0x142, 0xa>(x);   // row_bcast:15 -> rows 1,3
    x = dpp_add<0x143, 0xc>(x);   // row_bcast:31 -> rows 2,3
    return x;
}

__global__ __launch_bounds__(BLK, 8)
void cope_kernel(const float* __restrict__ query,     // [R, D]
                 const float* __restrict__ attn,      // [R, K]
                 const float* __restrict__ pos_emb,   // [D, NPOS]
                 const int*   __restrict__ npos_max_p,
                 float* __restrict__ out)              // [R, K]
{
    const int t    = threadIdx.x;
    const int wv   = t >> 6;       // wave id 0..15
    const int lane = t & 63;

    __shared__ float s_tab[RPB][NPOS + 1];   // +1 sentinel col

    const size_t row_base = (size_t)blockIdx.x * RPB;

    // ---------------- Phase 1: table GEMM via bf16 MFMA (R8 verbatim) ------
    {
        const int m  = lane & 15;
        const int g  = lane >> 4;
        const int n0 = wv * 32 + m;

        f32x4 acc0 = {0.f, 0.f, 0.f, 0.f};
        f32x4 acc1 = {0.f, 0.f, 0.f, 0.f};

        #pragma unroll
        for (int kk = 0; kk < 4; ++kk) {
            const int k0 = kk * 32 + g * 8;

            const float* qp = query + (row_base + m) * DD + k0;
            f32x4 a0 = *reinterpret_cast<const f32x4*>(qp);
            f32x4 a1 = *reinterpret_cast<const f32x4*>(qp + 4);
            BfPack af;
            af.u[0] = pack_bf16(a0.x, a0.y);
            af.u[1] = pack_bf16(a0.z, a0.w);
            af.u[2] = pack_bf16(a1.x, a1.y);
            af.u[3] = pack_bf16(a1.z, a1.w);

            const float* bp = pos_emb + (size_t)k0 * NPOS + n0;
            float b0[8], b1[8];
            #pragma unroll
            for (int j = 0; j < 8; ++j) {
                b0[j] = bp[(size_t)j * NPOS];
                b1[j] = bp[(size_t)j * NPOS + 16];
            }
            BfPack bf0, bf1;
            #pragma unroll
            for (int j = 0; j < 4; ++j) {
                bf0.u[j] = pack_bf16(b0[2 * j], b0[2 * j + 1]);
                bf1.u[j] = pack_bf16(b1[2 * j], b1[2 * j + 1]);
            }

            acc0 = __builtin_amdgcn_mfma_f32_16x16x32_bf16(af.v, bf0.v, acc0, 0, 0, 0);
            acc1 = __builtin_amdgcn_mfma_f32_16x16x32_bf16(af.v, bf1.v, acc1, 0, 0, 0);
        }

        #pragma unroll
        for (int r = 0; r < 4; ++r) {
            s_tab[g * 4 + r][n0]      = acc0[r];
            s_tab[g * 4 + r][n0 + 16] = acc1[r];
        }
        if (t < RPB) s_tab[t][NPOS] = 0.0f;   // sentinel
    }
    __syncthreads();

    // ---------------- Phase 2: streamed chunks + DPP scan ----------------
    // Reverse chunk order 7..0; scalar suffix carry `running`. Scan is pure
    // VALU (no LDS latency on carry chain); ~1 chunk of state live (no spill).
    const size_t row = row_base + wv;
    const float* arow = attn + row * (size_t)KK;
    float*       orow = out  + row * (size_t)KK;
    const float* tab  = s_tab[wv];

    const float clampv = (float)(*npos_max_p - 1);
    const int   la4    = lane * 4;

    f32x4 gv_a = *reinterpret_cast<const f32x4*>(arow + 7 * 256 + la4);
    f32x4 gv_b = *reinterpret_cast<const f32x4*>(arow + 6 * 256 + la4);

    float running = 0.0f;

    #pragma unroll
    for (int c = 7; c >= 0; --c) {
        f32x4 gv = gv_a;
        gv_a = gv_b;
        if (c >= 2)
            gv_b = *reinterpret_cast<const f32x4*>(arow + (c - 2) * 256 + la4);

        // sigmoid + in-lane inclusive suffix (4 elems)
        float p3 = sigmoidf_fast(gv.w);
        float p2 = sigmoidf_fast(gv.z) + p3;
        float p1 = sigmoidf_fast(gv.y) + p2;
        float p0 = sigmoidf_fast(gv.x) + p1;
        const float lct = p0;

        // wave prefix scan of lane totals: 6 dependent VALU adds (~24 cy)
        const float pfx = wave_prefix_incl(lct);
        const float Tc  = __int_as_float(
                              __builtin_amdgcn_readlane(__float_as_int(pfx), 63));

        // lanes strictly after me in this chunk = Tc - pfx
        const float base = running + (Tc - pfx);

        f32x4 res;
        float pel[4] = {p0, p1, p2, p3};
        #pragma unroll
        for (int j = 0; j < 4; ++j) {
            float pos = fminf(pel[j] + base, clampv);
            int   ifl = (int)pos;          // pos >= 0, trunc == floor
            float wgt = pos - (float)ifl;
            float lf  = tab[ifl];
            float lc  = tab[ifl + 1];      // sentinel makes ifl=511 safe
            res[j] = fmaf(wgt, lc - lf, lf);
        }
        __builtin_nontemporal_store(res,
            reinterpret_cast<f32x4*>(orow + c * 256 + la4));

        running += Tc;
    }
}

extern "C" void kernel_launch(void* const* d_in, const int* in_sizes, int n_in,
                              void* d_out, int out_size, void* d_ws, size_t ws_size,
                              hipStream_t stream) {
    const float* query   = (const float*)d_in[0];
    const float* attn    = (const float*)d_in[1];
    const float* pos_emb = (const float*)d_in[2];
    const int*   nposp   = (const int*)d_in[3];
    float*       outp    = (float*)d_out;

    const int rows   = in_sizes[1] / KK;   // B*H*Q = 49152
    const int blocks = rows / RPB;         // 3072

    cope_kernel<<<blocks, BLK, 0, stream>>>(query, attn, pos_emb, nposp, outp);
}

// Round 14
// 170.502 us; speedup vs baseline: 1.3863x; 1.1214x over previous
//
#include <hip/hip_runtime.h>
#include <math.h>

// Problem constants (B=2,H=12,Q=2048,K=2048,D=128,NPOS=512)
#define DD    128
#define NPOS  512
#define KK    2048
#define RPB   16        // rows per block = MFMA M dimension
#define BLK   1024      // 16 waves: one wave per row in phase 2

typedef __attribute__((ext_vector_type(8))) short short8_t;  // 8 bf16
typedef __attribute__((ext_vector_type(4))) float f32x4;

union BfPack {
    unsigned u[4];
    short8_t v;
};

__device__ __forceinline__ float sigmoidf_fast(float x) {
    return __builtin_amdgcn_rcpf(1.0f + __expf(-x));
}

__device__ __forceinline__ unsigned pack_bf16(float lo, float hi) {
    return (__float_as_uint(hi) & 0xffff0000u) | (__float_as_uint(lo) >> 16);
}

__global__ __launch_bounds__(BLK, 8)
void cope_kernel(const float* __restrict__ query,     // [R, D]
                 const float* __restrict__ attn,      // [R, K]
                 const float* __restrict__ pos_emb,   // [D, NPOS]
                 const int*   __restrict__ npos_max_p,
                 float* __restrict__ out)              // [R, K]
{
    const int t    = threadIdx.x;
    const int wv   = t >> 6;       // wave id 0..15
    const int lane = t & 63;

    __shared__ float s_tab[RPB][NPOS + 1];   // +1 sentinel col (repack reads it)

    const size_t row_base = (size_t)blockIdx.x * RPB;

    // ---------------- Phase 1: table GEMM via bf16 MFMA (R8 verbatim) ------
    {
        const int m  = lane & 15;
        const int g  = lane >> 4;
        const int n0 = wv * 32 + m;

        f32x4 acc0 = {0.f, 0.f, 0.f, 0.f};
        f32x4 acc1 = {0.f, 0.f, 0.f, 0.f};

        #pragma unroll
        for (int kk = 0; kk < 4; ++kk) {
            const int k0 = kk * 32 + g * 8;

            const float* qp = query + (row_base + m) * DD + k0;
            f32x4 a0 = *reinterpret_cast<const f32x4*>(qp);
            f32x4 a1 = *reinterpret_cast<const f32x4*>(qp + 4);
            BfPack af;
            af.u[0] = pack_bf16(a0.x, a0.y);
            af.u[1] = pack_bf16(a0.z, a0.w);
            af.u[2] = pack_bf16(a1.x, a1.y);
            af.u[3] = pack_bf16(a1.z, a1.w);

            const float* bp = pos_emb + (size_t)k0 * NPOS + n0;
            float b0[8], b1[8];
            #pragma unroll
            for (int j = 0; j < 8; ++j) {
                b0[j] = bp[(size_t)j * NPOS];
                b1[j] = bp[(size_t)j * NPOS + 16];
            }
            BfPack bf0, bf1;
            #pragma unroll
            for (int j = 0; j < 4; ++j) {
                bf0.u[j] = pack_bf16(b0[2 * j], b0[2 * j + 1]);
                bf1.u[j] = pack_bf16(b1[2 * j], b1[2 * j + 1]);
            }

            acc0 = __builtin_amdgcn_mfma_f32_16x16x32_bf16(af.v, bf0.v, acc0, 0, 0, 0);
            acc1 = __builtin_amdgcn_mfma_f32_16x16x32_bf16(af.v, bf1.v, acc1, 0, 0, 0);
        }

        #pragma unroll
        for (int r = 0; r < 4; ++r) {
            s_tab[g * 4 + r][n0]      = acc0[r];
            s_tab[g * 4 + r][n0 + 16] = acc1[r];
        }
        if (t < RPB) s_tab[t][NPOS] = 0.0f;   // sentinel
    }
    __syncthreads();

    // ---------------- Phase 1.5: repack table to bf16 pairs (in place) -----
    // Entry n of row wv becomes pack(tab[n], tab[n+1]) as 2x bf16 in 1 dword.
    // Wave wv repacks its own phase-2 row. Read pairs -> barrier -> write.
    {
        float lo[8], hi[8];
        #pragma unroll
        for (int j = 0; j < 8; ++j) {
            const int e = lane + j * 64;
            lo[j] = s_tab[wv][e];
            hi[j] = s_tab[wv][e + 1];    // e=511 reads the sentinel
        }
        __syncthreads();
        unsigned* urow = reinterpret_cast<unsigned*>(s_tab[wv]);
        #pragma unroll
        for (int j = 0; j < 8; ++j)
            urow[lane + j * 64] = pack_bf16(lo[j], hi[j]);
    }
    __syncthreads();

    // ---------------- Phase 2: per-wave suffix scan + packed gather --------
    const size_t row = row_base + wv;
    const float* arow = attn + row * (size_t)KK;
    float*       orow = out  + row * (size_t)KK;
    const unsigned* utab = reinterpret_cast<const unsigned*>(s_tab[wv]);

    const float clampv = (float)(*npos_max_p - 1);

    float suff[8][4];   // within-lane suffix sums (inclusive)
    float lct[8];       // lane-chunk totals
    float incl[8];      // wave-suffix-inclusive scan of lane totals

    #pragma unroll
    for (int c = 0; c < 8; ++c) {
        f32x4 gv = *reinterpret_cast<const f32x4*>(arow + c * 256 + lane * 4);
        float s0 = sigmoidf_fast(gv.x);
        float s1 = sigmoidf_fast(gv.y);
        float s2 = sigmoidf_fast(gv.z);
        float s3 = sigmoidf_fast(gv.w);
        suff[c][3] = s3;
        suff[c][2] = s2 + suff[c][3];
        suff[c][1] = s1 + suff[c][2];
        suff[c][0] = s0 + suff[c][1];
        lct[c] = suff[c][0];

        // wave-level inclusive suffix scan (64 lanes) — R8 verbatim
        float v = lct[c];
        #pragma unroll
        for (int off = 1; off < 64; off <<= 1) {
            float u = __shfl_down(v, off);
            if (lane + off < 64) v += u;
        }
        incl[c] = v;
    }

    float Tc[8];
    #pragma unroll
    for (int c = 0; c < 8; ++c) Tc[c] = __shfl(incl[c], 0);
    float offc[8];
    offc[7] = 0.0f;
    #pragma unroll
    for (int c = 6; c >= 0; --c) offc[c] = offc[c + 1] + Tc[c + 1];

    #pragma unroll
    for (int c = 0; c < 8; ++c) {
        float base = offc[c] + (incl[c] - lct[c]);
        f32x4 res;
        #pragma unroll
        for (int j = 0; j < 4; ++j) {
            float pos = fminf(suff[c][j] + base, clampv);
            int   ifl = (int)pos;          // pos >= 0, trunc == floor
            float wgt = pos - (float)ifl;
            unsigned u = utab[ifl];        // one ds_read_b32: (tab[i],tab[i+1])
            float lf = __uint_as_float(u << 16);
            float lc = __uint_as_float(u & 0xffff0000u);
            res[j] = fmaf(wgt, lc - lf, lf);
        }
        __builtin_nontemporal_store(res, reinterpret_cast<f32x4*>(orow + c * 256 + lane * 4));
    }
}

extern "C" void kernel_launch(void* const* d_in, const int* in_sizes, int n_in,
                              void* d_out, int out_size, void* d_ws, size_t ws_size,
                              hipStream_t stream) {
    const float* query   = (const float*)d_in[0];
    const float* attn    = (const float*)d_in[1];
    const float* pos_emb = (const float*)d_in[2];
    const int*   nposp   = (const int*)d_in[3];
    float*       outp    = (float*)d_out;

    const int rows   = in_sizes[1] / KK;   // B*H*Q = 49152
    const int blocks = rows / RPB;         // 3072

    cope_kernel<<<blocks, BLK, 0, stream>>>(query, attn, pos_emb, nposp, outp);
}